// Round 1
// baseline (247.721 us; speedup 1.0000x reference)
//
#include <hip/hip_runtime.h>
#include <cstdint>

typedef __attribute__((ext_vector_type(8)))  short bf16x8;   // 8 x bf16 (4 VGPR)
typedef __attribute__((ext_vector_type(16))) float f32x16;   // MFMA 32x32 acc

__device__ __forceinline__ unsigned short f2bf(float x) {    // RNE fp32->bf16
  unsigned u = __float_as_uint(x);
  u += 0x7fffu + ((u >> 16) & 1u);
  return (unsigned short)(u >> 16);
}
__device__ __forceinline__ float bf2f(unsigned short h) {
  return __uint_as_float(((unsigned)h) << 16);
}
__device__ __forceinline__ float silu_f(float v) {
  return v * __builtin_amdgcn_rcpf(1.0f + __expf(-v));
}

// ---------------- time MLP: temb_pad[b][144] = [0 x6, silu(sinemb(t)@tw+tb), 0 x10] ----
__global__ void time_kernel(const float* __restrict__ t, const float* __restrict__ tw,
                            const float* __restrict__ tb,
                            unsigned short* __restrict__ temb_pad) {
  __shared__ float e[128];
  const int b = blockIdx.x, j = threadIdx.x;
  const float tv = t[b];
  const int i = (j < 64) ? j : (j - 64);
  const float f = expf(-0.14619588396823767f * (float)i);  // log(1e4)/63
  const float ang = tv * f;
  e[j] = (j < 64) ? sinf(ang) : cosf(ang);
  __syncthreads();
  float acc = tb[j];
#pragma unroll 8
  for (int k = 0; k < 128; ++k) acc += e[k] * tw[k * 128 + j];
  unsigned short* row = temb_pad + b * 144;
  row[6 + j] = f2bf(silu_f(acc));
  if (j < 6)  row[j] = 0;
  if (j < 10) row[134 + j] = 0;
}

// ---------------- pack W0/W1/W2 into MFMA B-fragment order, bf16, K0 padded 134->144 ----
// layout: [layer][group g(64 cols)][kt][t(32-col tile)][lane][8]  -> linear 16B/lane chunks
__global__ void pack_kernel(const float* __restrict__ W0, const float* __restrict__ W1,
                            const float* __restrict__ W2,
                            unsigned short* __restrict__ packW) {
  const int idx = blockIdx.x * 256 + threadIdx.x;          // 0..167935
  const float* W; int KT, kmax, lidx;
  if (idx < 36864)        { W = W0; KT = 9;  kmax = 134; lidx = idx; }
  else if (idx < 102400)  { W = W1; KT = 16; kmax = 256; lidx = idx - 36864; }
  else                    { W = W2; KT = 16; kmax = 256; lidx = idx - 102400; }
  const int per_g = KT * 1024;
  const int g  = lidx / per_g;
  int r        = lidx % per_g;
  const int kt = r / 1024;  r %= 1024;
  const int tt = r / 512;   r %= 512;
  const int l  = r >> 3, jj = r & 7;
  const int k   = kt * 16 + ((l >> 5) << 3) + jj;          // B-frag: k = 8*(lane>>5)+j
  const int col = ((2 * g + tt) << 5) + (l & 31);          //         n = lane&31
  const float v = (k < kmax) ? W[k * 256 + col] : 0.0f;
  packW[idx] = f2bf(v);
}

// ---------------- one GCN layer, fully fused per graph ----------------
template <int KT, int LAYER>
__device__ __forceinline__ void gcn_layer(
    const int tid, const int w, const int lane, const int q, const int c,
    const unsigned short* packL, const float* BIAS,
    const bf16x8* Aold, bf16x8* Anew,
    unsigned short* lds_w, unsigned short* bnd,
    unsigned short* scr_w, float* pool) {
#pragma unroll
  for (int g = 0; g < 4; ++g) {
    { // stage this 64-col group's W (KT*2KiB) into LDS, linear copy
      const uint4* src = (const uint4*)packL + g * (KT * 128);
      uint4* dst = (uint4*)lds_w;
      for (int ci = tid; ci < KT * 128; ci += 512) dst[ci] = src[ci];
    }
    __syncthreads();

    // matmul: wave's 32 nodes x 64 cols, A register-resident, B from LDS
    f32x16 acc[2];
#pragma unroll
    for (int i = 0; i < 16; ++i) { acc[0][i] = 0.f; acc[1][i] = 0.f; }
    const bf16x8* wb = (const bf16x8*)lds_w;
#pragma unroll
    for (int kt = 0; kt < KT; ++kt) {
      bf16x8 bf0 = wb[(kt * 2 + 0) * 64 + lane];
      bf16x8 bf1 = wb[(kt * 2 + 1) * 64 + lane];
      acc[0] = __builtin_amdgcn_mfma_f32_32x32x16_bf16(Aold[kt], bf0, acc[0], 0, 0, 0);
      acc[1] = __builtin_amdgcn_mfma_f32_32x32x16_bf16(Aold[kt], bf1, acc[1], 0, 0, 0);
    }

    // publish wave-boundary s rows (node 32w = C/D reg0@q0, node 32w+31 = reg15@q1)
    {
      const int C0 = g * 64 + c, C1 = C0 + 32;
      if (q == 0) { bnd[(w * 2 + 0) * 256 + C0] = f2bf(acc[0][0]);
                    bnd[(w * 2 + 0) * 256 + C1] = f2bf(acc[1][0]); }
      else        { bnd[(w * 2 + 1) * 256 + C0] = f2bf(acc[0][15]);
                    bnd[(w * 2 + 1) * 256 + C1] = f2bf(acc[1][15]); }
    }
    __syncthreads();

    // aggregate (cyclic 3-tap) + bias + silu; then transpose->A-frags or pool
#pragma unroll
    for (int t = 0; t < 2; ++t) {
      const int C = g * 64 + t * 32 + c;
      float xch[16];
#pragma unroll
      for (int r = 0; r < 16; ++r)
        if ((r & 3) == 0 || (r & 3) == 3) xch[r] = __shfl_xor(acc[t][r], 32);
      const float bp   = bf2f(bnd[(((w + 7) & 7) * 2 + 1) * 256 + C]); // node 32w-1
      const float bn   = bf2f(bnd[(((w + 1) & 7) * 2 + 0) * 256 + C]); // node 32w+32
      const float bias = BIAS[C];
      float yv[16];
      float psum = 0.f;
#pragma unroll
      for (int r = 0; r < 16; ++r) {
        const int p = r & 3, a = r >> 2;   // C/D row = p + 8a + 4q
        float prev, next;
        if (p > 0)      prev = acc[t][r - 1];
        else if (a > 0) prev = q ? xch[a * 4 + 3] : xch[a * 4 - 1];
        else            prev = q ? xch[3] : bp;
        if (p < 3)      next = acc[t][r + 1];
        else if (a < 3) next = q ? xch[a * 4 + 4] : xch[a * 4];
        else            next = q ? bn : xch[12];
        const float v = (prev + acc[t][r] + next) * 0.33333333333f + bias;
        const float y = silu_f(v);
        if constexpr (LAYER == 2) { psum += y; (void)yv; } else { yv[r] = y; }
      }
      if constexpr (LAYER == 2) {
        psum += __shfl_xor(psum, 32);
        if (q == 0) atomicAdd(&pool[C], psum);
      } else {
        __syncthreads();  // scr write-after-read safety (prev tile's frag reads)
#pragma unroll
        for (int r = 0; r < 16; ++r) {
          const int row = (r & 3) + (r >> 2) * 8 + q * 4;
          scr_w[row * 40 + c] = f2bf(yv[r]);     // row stride 40 shorts (80B, 16B-mult)
        }
        __syncthreads();  // make whole-wave scratch visible
        // A-frag: m=lane&31(=c), k=8q+j ; this group's 64 cols = k-tiles 4g..4g+3
        Anew[g * 4 + t * 2 + 0] = *(const bf16x8*)(scr_w + c * 40 + q * 8);
        Anew[g * 4 + t * 2 + 1] = *(const bf16x8*)(scr_w + c * 40 + 16 + q * 8);
      }
    }
  }
}

// ---------------- main fused kernel: 1 block = 1 graph, 8 waves x 32 nodes ----------
__global__ __launch_bounds__(512, 2) void poly_kernel(
    const float* __restrict__ x,
    const unsigned short* __restrict__ temb_pad,
    const unsigned short* __restrict__ packW,
    const float* __restrict__ B0, const float* __restrict__ B1,
    const float* __restrict__ B2, float* __restrict__ out) {
  __shared__ __align__(16) unsigned short lds_w[16 * 1024];  // 32 KiB W stage
  __shared__ unsigned short bnd[8 * 2 * 256];                //  8 KiB boundary rows (bf16)
  __shared__ __align__(16) unsigned short scr[8 * 1280];     // 20 KiB per-wave transpose
  __shared__ float pool[256];                                //  1 KiB mean-pool

  const int tid = threadIdx.x;
  const int w = tid >> 6, lane = tid & 63;
  const int q = lane >> 5, c = lane & 31;
  const int b = blockIdx.x;

  if (tid < 256) pool[tid] = 0.f;

  // build layer-0 A fragments: [coords(2), pe(4), temb(128), pad0(10)] = K 144
  bf16x8 A0[9], A1[16], A2[16];
  {
    const bf16x8* tp = (const bf16x8*)(temb_pad + b * 144);
#pragma unroll
    for (int kt = 0; kt < 9; ++kt) A0[kt] = tp[kt * 2 + q];
    if (q == 0) {  // k=0..5 live in q==0 lanes of k-tile 0
      const int n = w * 32 + c;                    // global node = A row m
      const float cx = x[b * 512 + 2 * n];
      const float cy = x[b * 512 + 2 * n + 1];
      const float th = 0.024543692605870074f * (float)n;   // 2*pi/256
      A0[0][0] = (short)f2bf(cx);
      A0[0][1] = (short)f2bf(cy);
      A0[0][2] = (short)f2bf(sinf(th));
      A0[0][3] = (short)f2bf(cosf(th));
      A0[0][4] = (short)f2bf(sinf(2.f * th));
      A0[0][5] = (short)f2bf(cosf(2.f * th));
    }
  }

  unsigned short* scr_w = scr + w * 1280;
  gcn_layer< 9, 0>(tid, w, lane, q, c, packW,          B0, A0, A1, lds_w, bnd, scr_w, pool);
  gcn_layer<16, 1>(tid, w, lane, q, c, packW + 36864,  B1, A1, A2, lds_w, bnd, scr_w, pool);
  gcn_layer<16, 2>(tid, w, lane, q, c, packW + 102400, B2, A2, A1, lds_w, bnd, scr_w, pool);

  __syncthreads();
  if (tid < 256) out[b * 256 + tid] = pool[tid] * (1.f / 256.f);
}

// ---------------- launch ----------------
extern "C" void kernel_launch(void* const* d_in, const int* in_sizes, int n_in,
                              void* d_out, int out_size, void* d_ws, size_t ws_size,
                              hipStream_t stream) {
  const float* x  = (const float*)d_in[0];
  const float* t  = (const float*)d_in[1];
  const float* tw = (const float*)d_in[2];
  const float* tb = (const float*)d_in[3];
  const float* W0 = (const float*)d_in[4];
  const float* b0 = (const float*)d_in[5];
  const float* W1 = (const float*)d_in[6];
  const float* b1 = (const float*)d_in[7];
  const float* W2 = (const float*)d_in[8];
  const float* b2 = (const float*)d_in[9];

  unsigned short* wsp      = (unsigned short*)d_ws;
  unsigned short* temb_pad = wsp;            // 1024*144 shorts
  unsigned short* packW    = wsp + 147456;   // 167936 shorts (W0:36864, W1:65536, W2:65536)
  float* out = (float*)d_out;

  time_kernel<<<1024, 128, 0, stream>>>(t, tw, tb, temb_pad);
  pack_kernel<<<656, 256, 0, stream>>>(W0, W1, W2, packW);
  poly_kernel<<<1024, 512, 0, stream>>>(x, temb_pad, packW, b0, b1, b2, out);
}

// Round 2
// 230.944 us; speedup vs baseline: 1.0726x; 1.0726x over previous
//
#include <hip/hip_runtime.h>
#include <cstdint>

typedef __attribute__((ext_vector_type(8)))  short bf16x8;   // 8 x bf16 (4 VGPR)
typedef __attribute__((ext_vector_type(16))) float f32x16;   // MFMA 32x32 acc

__device__ __forceinline__ unsigned short f2bf(float x) {    // RNE fp32->bf16
  unsigned u = __float_as_uint(x);
  u += 0x7fffu + ((u >> 16) & 1u);
  return (unsigned short)(u >> 16);
}
__device__ __forceinline__ float bf2f(unsigned short h) {
  return __uint_as_float(((unsigned)h) << 16);
}
__device__ __forceinline__ float silu_f(float v) {
  return v * __builtin_amdgcn_rcpf(1.0f + __expf(-v));
}
// async global->LDS, 16B per lane; lds ptr must be wave-uniform base (+lane*16 implied)
__device__ __forceinline__ void gl_lds16(const unsigned short* g, unsigned short* l) {
  __builtin_amdgcn_global_load_lds(
      (const __attribute__((address_space(1))) unsigned int*)g,
      (__attribute__((address_space(3))) unsigned int*)l, 16, 0, 0);
}

// ---- pack W0/W1/W2 into MFMA B-frag order, bf16, K0 padded 134->144.
// Group (64 cols) = [half t:{tile0,tile1}][kt][lane 0..63][j 0..7]; halves are
// contiguous so tile0 can be LDS-staged and tile1 streamed from global/L2.
__global__ void pack_kernel(const float* __restrict__ W0, const float* __restrict__ W1,
                            const float* __restrict__ W2,
                            unsigned short* __restrict__ packW) {
  const int idx = blockIdx.x * 256 + threadIdx.x;          // 0..167935
  const float* W; int KT, kmax, lidx;
  if (idx < 36864)        { W = W0; KT = 9;  kmax = 134; lidx = idx; }
  else if (idx < 102400)  { W = W1; KT = 16; kmax = 256; lidx = idx - 36864; }
  else                    { W = W2; KT = 16; kmax = 256; lidx = idx - 102400; }
  const int per_g = KT * 1024;
  const int g  = lidx / per_g;
  int r        = lidx % per_g;
  const int half = KT * 512;
  const int t  = r / half;  r %= half;
  const int kt = r / 512;   r %= 512;
  const int l  = r >> 3, jj = r & 7;
  const int k   = kt * 16 + ((l >> 5) << 3) + jj;          // B-frag: k = 8*(lane>>5)+j
  const int col = g * 64 + t * 32 + (l & 31);              //         n = lane&31
  const float v = (k < kmax) ? W[k * 256 + col] : 0.0f;
  packW[idx] = f2bf(v);
}

// ---------------- one GCN layer, fully fused per graph ----------------
template <int KT, int LAYER>
__device__ __forceinline__ void gcn_layer(
    const int tid, const int w, const int lane, const int q, const int c,
    const unsigned short* __restrict__ packL, const float* __restrict__ BIAS,
    const bf16x8* Aold, bf16x8* Anew,
    unsigned short* lds_w, unsigned short* bnd,
    unsigned short* scr_w, float* poolw) {
#pragma unroll
  for (int g = 0; g < 4; ++g) {
    const unsigned short* srcg = packL + g * (KT * 1024);
    { // stage tile-0 half (KT*64 x 16B) into LDS via async global_load_lds
      const int total = KT * 64;                  // uint4 chunks; multiple of 64
      for (int it = 0; it * 512 < total; ++it) {
        const int ci = it * 512 + tid;
        if (ci < total)                           // wave-uniform guard
          gl_lds16(srcg + ci * 8, lds_w + (it * 512 + w * 64) * 8);
      }
    }
    __syncthreads();  // staging visible (vmcnt drain); prev-group reads done via last barrier

    // matmul: wave's 32 nodes x 64 cols; A register-resident;
    // tile0 B from LDS, tile1 B direct from global (L2-resident) -> splits DS/VMEM pipes
    f32x16 acc[2];
#pragma unroll
    for (int i = 0; i < 16; ++i) { acc[0][i] = 0.f; acc[1][i] = 0.f; }
    {
      const bf16x8* wb0 = (const bf16x8*)lds_w;           // [kt][lane]
      const bf16x8* wb1 = (const bf16x8*)(srcg + KT * 512);
#pragma unroll
      for (int kt = 0; kt < KT; ++kt) {
        bf16x8 b0 = wb0[kt * 64 + lane];
        bf16x8 b1 = wb1[kt * 64 + lane];
        acc[0] = __builtin_amdgcn_mfma_f32_32x32x16_bf16(Aold[kt], b0, acc[0], 0, 0, 0);
        acc[1] = __builtin_amdgcn_mfma_f32_32x32x16_bf16(Aold[kt], b1, acc[1], 0, 0, 0);
      }
    }

    // publish wave-boundary s rows (node 32w = C/D reg0@q0, node 32w+31 = reg15@q1)
    {
      const int C0 = g * 64 + c, C1 = C0 + 32;
      if (q == 0) { bnd[(w * 2 + 0) * 256 + C0] = f2bf(acc[0][0]);
                    bnd[(w * 2 + 0) * 256 + C1] = f2bf(acc[1][0]); }
      else        { bnd[(w * 2 + 1) * 256 + C0] = f2bf(acc[0][15]);
                    bnd[(w * 2 + 1) * 256 + C1] = f2bf(acc[1][15]); }
    }
    __syncthreads();  // the only cross-wave dependency (bnd)

    // aggregate (cyclic 3-tap) + bias + silu; transpose->A-frags (same-wave DS, no barriers)
#pragma unroll
    for (int t = 0; t < 2; ++t) {
      const int C = g * 64 + t * 32 + c;
      float xch[16];
#pragma unroll
      for (int r = 0; r < 16; ++r)
        if ((r & 3) == 0 || (r & 3) == 3) xch[r] = __shfl_xor(acc[t][r], 32);
      const float bp   = bf2f(bnd[(((w + 7) & 7) * 2 + 1) * 256 + C]); // node 32w-1
      const float bn   = bf2f(bnd[(((w + 1) & 7) * 2 + 0) * 256 + C]); // node 32w+32
      const float bias = BIAS[C];
      float yv[16];
      float psum = 0.f;
#pragma unroll
      for (int r = 0; r < 16; ++r) {
        const int p = r & 3, a = r >> 2;   // C/D row = p + 8a + 4q
        float prev, next;
        if (p > 0)      prev = acc[t][r - 1];
        else if (a > 0) prev = q ? xch[a * 4 + 3] : xch[a * 4 - 1];
        else            prev = q ? xch[3] : bp;
        if (p < 3)      next = acc[t][r + 1];
        else if (a < 3) next = q ? xch[a * 4 + 4] : xch[a * 4];
        else            next = q ? bn : xch[12];
        const float v = (prev + acc[t][r] + next) * 0.33333333333f + bias;
        const float y = silu_f(v);
        if constexpr (LAYER == 2) { psum += y; (void)yv; } else { yv[r] = y; }
      }
      if constexpr (LAYER == 2) {
        psum += __shfl_xor(psum, 32);
        if (q == 0) poolw[w * 256 + C] = psum;   // per-wave partial, no atomics
      } else {
        // per-wave scratch: DS pipe is in-order per wave -> no __syncthreads needed
#pragma unroll
        for (int r = 0; r < 16; ++r) {
          const int row = (r & 3) + (r >> 2) * 8 + q * 4;
          scr_w[row * 40 + c] = f2bf(yv[r]);     // stride 40 shorts (80B, 16B-mult)
        }
        // A-frag: m=lane&31(=c), k=8q+j ; this group's 64 cols = k-tiles 4g..4g+3
        Anew[g * 4 + t * 2 + 0] = *(const bf16x8*)(scr_w + c * 40 + q * 8);
        Anew[g * 4 + t * 2 + 1] = *(const bf16x8*)(scr_w + c * 40 + 16 + q * 8);
      }
    }
  }
}

// ---------------- main fused kernel: 1 block = 1 graph, 8 waves x 32 nodes ----------
__global__ __launch_bounds__(512, 2) void poly_kernel(
    const float* __restrict__ x, const float* __restrict__ t,
    const float* __restrict__ tw, const float* __restrict__ tb,
    const unsigned short* __restrict__ packW,
    const float* __restrict__ B0, const float* __restrict__ B1,
    const float* __restrict__ B2, float* __restrict__ out) {
  __shared__ __align__(16) unsigned short lds_w[8192];     // 16 KiB W tile-0 stage
  __shared__ __align__(16) unsigned short bnd[4096];       //  8 KiB boundary rows (bf16)
  __shared__ __align__(16) unsigned short scr[10240];      // 20 KiB per-wave transpose / pool
  __shared__ __align__(16) unsigned short temb_sh[160];    // padded time embedding (bf16)

  const int tid = threadIdx.x;
  const int w = tid >> 6, lane = tid & 63;
  const int q = lane >> 5, c = lane & 31;
  const int b = blockIdx.x;

  // ---- fused time MLP: temb = silu(sinemb(t[b]) @ tw + tb), padded [0x6, ., 0x10] ----
  {
    float* e_sh = (float*)bnd;        // 128 floats, bnd unused yet
    float* part = (float*)scr;        // 512 float partials, scr unused yet
    if (tid < 128) {
      const float tv = t[b];
      const int i = tid & 63;
      const float f = expf(-0.14619588396823767f * (float)i);  // log(1e4)/63
      const float ang = tv * f;
      e_sh[tid] = (tid < 64) ? sinf(ang) : cosf(ang);
    }
    __syncthreads();
    {
      const int j = tid & 127, p = tid >> 7;   // 4-way k-split over the block
      float a = 0.f;
#pragma unroll 8
      for (int kk = 0; kk < 32; ++kk) {
        const int k = p * 32 + kk;
        a += e_sh[k] * tw[k * 128 + j];
      }
      part[tid] = a;
    }
    __syncthreads();
    if (tid < 128) {
      const float a = tb[tid] + part[tid] + part[128 + tid] + part[256 + tid] + part[384 + tid];
      temb_sh[6 + tid] = f2bf(silu_f(a));
      if (tid < 6)  temb_sh[tid] = 0;
      if (tid < 10) temb_sh[134 + tid] = 0;
    }
    __syncthreads();
  }

  // build layer-0 A fragments: [coords(2), pe(4), temb(128), pad0(10)] = K 144
  bf16x8 A0[9], A1[16], A2[16];
  {
#pragma unroll
    for (int kt = 0; kt < 9; ++kt)
      A0[kt] = *(const bf16x8*)(temb_sh + kt * 16 + q * 8);
    if (q == 0) {  // k=0..5 live in q==0 lanes of k-tile 0
      const int n = w * 32 + c;                    // global node = A row m
      const float cx = x[b * 512 + 2 * n];
      const float cy = x[b * 512 + 2 * n + 1];
      const float th = 0.024543692605870074f * (float)n;   // 2*pi/256
      A0[0][0] = (short)f2bf(cx);
      A0[0][1] = (short)f2bf(cy);
      A0[0][2] = (short)f2bf(sinf(th));
      A0[0][3] = (short)f2bf(cosf(th));
      A0[0][4] = (short)f2bf(sinf(2.f * th));
      A0[0][5] = (short)f2bf(cosf(2.f * th));
    }
  }

  unsigned short* scr_w = scr + w * 1280;
  float* poolw = (float*)scr;   // layer-2 per-wave pool partials (transpose data dead by then)
  gcn_layer< 9, 0>(tid, w, lane, q, c, packW,          B0, A0, A1, lds_w, bnd, scr_w, poolw);
  gcn_layer<16, 1>(tid, w, lane, q, c, packW + 36864,  B1, A1, A2, lds_w, bnd, scr_w, poolw);
  gcn_layer<16, 2>(tid, w, lane, q, c, packW + 102400, B2, A2, A1, lds_w, bnd, scr_w, poolw);

  __syncthreads();
  if (tid < 256) {
    float s = 0.f;
#pragma unroll
    for (int ww = 0; ww < 8; ++ww) s += poolw[ww * 256 + tid];
    out[b * 256 + tid] = s * (1.f / 256.f);
  }
}

// ---------------- launch ----------------
extern "C" void kernel_launch(void* const* d_in, const int* in_sizes, int n_in,
                              void* d_out, int out_size, void* d_ws, size_t ws_size,
                              hipStream_t stream) {
  const float* x  = (const float*)d_in[0];
  const float* t  = (const float*)d_in[1];
  const float* tw = (const float*)d_in[2];
  const float* tb = (const float*)d_in[3];
  const float* W0 = (const float*)d_in[4];
  const float* b0 = (const float*)d_in[5];
  const float* W1 = (const float*)d_in[6];
  const float* b1 = (const float*)d_in[7];
  const float* W2 = (const float*)d_in[8];
  const float* b2 = (const float*)d_in[9];

  unsigned short* packW = (unsigned short*)d_ws;   // 167936 shorts (W0:36864, W1:65536, W2:65536)
  float* out = (float*)d_out;

  pack_kernel<<<656, 256, 0, stream>>>(W0, W1, W2, packW);
  poly_kernel<<<1024, 512, 0, stream>>>(x, t, tw, tb, packW, b0, b1, b2, out);
}

// Round 3
// 230.595 us; speedup vs baseline: 1.0743x; 1.0015x over previous
//
#include <hip/hip_runtime.h>
#include <cstdint>

typedef __attribute__((ext_vector_type(8)))  short bf16x8;   // 8 x bf16 (4 VGPR)
typedef __attribute__((ext_vector_type(16))) float f32x16;   // MFMA 32x32 acc
typedef __attribute__((ext_vector_type(2)))  float f32x2;
typedef __attribute__((ext_vector_type(4)))  int   i32x4;

__device__ __forceinline__ unsigned short f2bf(float x) {    // RNE fp32->bf16
  unsigned u = __float_as_uint(x);
  u += 0x7fffu + ((u >> 16) & 1u);
  return (unsigned short)(u >> 16);
}
__device__ __forceinline__ float bf2f(unsigned short h) {
  return __uint_as_float(((unsigned)h) << 16);
}
__device__ __forceinline__ float silu_f(float v) {
  return v * __builtin_amdgcn_rcpf(1.0f + __expf(-v));
}
// pack two fp32 -> bf16x2 dword (lo = first arg), HW cvt if available
__device__ __forceinline__ unsigned pk2bf(float lo, float hi) {
#if defined(__has_builtin)
#if __has_builtin(__builtin_amdgcn_cvt_pk_bf16_f32)
  auto v = __builtin_amdgcn_cvt_pk_bf16_f32(lo, hi);
  unsigned u; __builtin_memcpy(&u, &v, 4); return u;
#else
  return ((unsigned)f2bf(hi) << 16) | (unsigned)f2bf(lo);
#endif
#else
  return ((unsigned)f2bf(hi) << 16) | (unsigned)f2bf(lo);
#endif
}
// v_perm lane-local byte select: result = x.lo16 | y.lo16<<16  (and hi version)
__device__ __forceinline__ unsigned lo_pack(unsigned x, unsigned y) {
  return __builtin_amdgcn_perm(y, x, 0x05040100u);
}
__device__ __forceinline__ unsigned hi_pack(unsigned x, unsigned y) {
  return __builtin_amdgcn_perm(y, x, 0x07060302u);
}
// async global->LDS, 16B/lane; lds ptr is wave-uniform base (+lane*16 implied)
__device__ __forceinline__ void gl_lds16(const unsigned short* g, unsigned short* l) {
  __builtin_amdgcn_global_load_lds(
      (const __attribute__((address_space(1))) unsigned int*)g,
      (__attribute__((address_space(3))) unsigned int*)l, 16, 0, 0);
}
// stage `chunks` 16B-chunks (chunks % 64 == 0) into lds_w
__device__ __forceinline__ void stage(const unsigned short* src, unsigned short* lds_w,
                                      const int tid, const int w, const int chunks) {
  for (int it = 0; it * 512 < chunks; ++it) {
    const int ci = it * 512 + tid;
    if (ci < chunks)                              // wave-uniform split (chunks%64==0)
      gl_lds16(src + ci * 8, lds_w + (it * 512 + w * 64) * 8);
  }
}

// ---- pack W0/W1/W2 into MFMA B-frag order, bf16, K0 padded 134->144 (coalesced reads).
// layout: [layer][g(64 cols)][t(32-col tile)][kt][lane][8]
__global__ void pack_kernel(const float* __restrict__ W0, const float* __restrict__ W1,
                            const float* __restrict__ W2,
                            unsigned short* __restrict__ packW) {
  const int idx = blockIdx.x * 256 + threadIdx.x;          // 0..167935
  const float* W; int KT, kmax, base, lidx;
  if (idx < 36864)        { W = W0; KT = 9;  kmax = 134; base = 0;      lidx = idx; }
  else if (idx < 102400)  { W = W1; KT = 16; kmax = 256; base = 36864;  lidx = idx - 36864; }
  else                    { W = W2; KT = 16; kmax = 256; base = 102400; lidx = idx - 102400; }
  const int k   = lidx >> 8;                               // row of W (padded)
  const int col = lidx & 255;
  const float v = (k < kmax) ? W[k * 256 + col] : 0.0f;    // coalesced read
  const int kt = k >> 4, kr = k & 15, q = kr >> 3, j = kr & 7;
  const int g = col >> 6, t = (col >> 5) & 1, n = col & 31;
  const int dest = base + g * (KT * 1024) + t * (KT * 512) + kt * 512 + (q * 32 + n) * 8 + j;
  packW[dest] = f2bf(v);
}

// ---------------- one GCN layer, fully fused per graph ----------------
template <int KT, int LAYER>
__device__ __forceinline__ void gcn_layer(
    const int tid, const int w, const int lane, const int q, const int c,
    const unsigned short* __restrict__ packL,
    const unsigned short* __restrict__ nextL, const int nextChunks,
    const float* __restrict__ BIAS,
    const bf16x8* Aold, bf16x8* Anew,
    unsigned short* lds_w, unsigned short* bnd,
    unsigned int* scr3_w, float* poolw) {
#pragma unroll
  for (int g = 0; g < 4; ++g) {
    __syncthreads();                    // stage(g) visible across waves; bnd parity safe
    const unsigned short* srcg = packL + g * (KT * 1024);

    // matmul: wave's 32 nodes x 64 cols; A register-resident;
    // tile0 B from LDS, tile1 B direct from global (L1/L2-resident)
    f32x16 acc0, acc1;
#pragma unroll
    for (int i = 0; i < 16; ++i) { acc0[i] = 0.f; acc1[i] = 0.f; }
    {
      const bf16x8* wb0 = (const bf16x8*)lds_w;
      const bf16x8* wb1 = (const bf16x8*)(srcg + KT * 512);
#pragma unroll
      for (int kt = 0; kt < KT; ++kt) {
        bf16x8 b0 = wb0[kt * 64 + lane];
        bf16x8 b1 = wb1[kt * 64 + lane];
        acc0 = __builtin_amdgcn_mfma_f32_32x32x16_bf16(Aold[kt], b0, acc0, 0, 0, 0);
        acc1 = __builtin_amdgcn_mfma_f32_32x32x16_bf16(Aold[kt], b1, acc1, 0, 0, 0);
      }
    }

    // publish wave-boundary s rows into bnd[par][w][e][64]
    unsigned short* bndp = bnd + (g & 1) * 2048;
    if (q == 0) { bndp[(w * 2 + 0) * 64 + c]      = f2bf(acc0[0]);
                  bndp[(w * 2 + 0) * 64 + 32 + c] = f2bf(acc1[0]); }
    else        { bndp[(w * 2 + 1) * 64 + c]      = f2bf(acc0[15]);
                  bndp[(w * 2 + 1) * 64 + 32 + c] = f2bf(acc1[15]); }
    __syncthreads();                    // all MFMA lds reads done + bnd visible

    // prefetch next group's (or next layer's) tile-0 W — overlaps the epilogue
    if (g < 3) stage(packL + (g + 1) * (KT * 1024), lds_w, tid, w, KT * 64);
    else if (nextChunks) stage(nextL, lds_w, tid, w, nextChunks);

    // ---- epilogue: cyclic 3-tap + bias + silu, both tiles together ----
    float x0[16], x1[16];
#pragma unroll
    for (int r = 0; r < 16; ++r)
      if ((r & 3) == 0 || (r & 3) == 3) {
        x0[r] = __shfl_xor(acc0[r], 32);
        x1[r] = __shfl_xor(acc1[r], 32);
      }
    const float bp0 = bf2f(bndp[(((w + 7) & 7) * 2 + 1) * 64 + c]);
    const float bp1 = bf2f(bndp[(((w + 7) & 7) * 2 + 1) * 64 + 32 + c]);
    const float bn0 = bf2f(bndp[(((w + 1) & 7) * 2 + 0) * 64 + c]);
    const float bn1 = bf2f(bndp[(((w + 1) & 7) * 2 + 0) * 64 + 32 + c]);
    const float bias0 = BIAS[g * 64 + c], bias1 = BIAS[g * 64 + 32 + c];
    const float T = 0.33333333333f;
    float ps0 = 0.f, ps1 = 0.f;
#pragma unroll
    for (int r = 0; r < 16; ++r) {
      const int p = r & 3, a = r >> 2;   // C/D row = p + 8a + 4q
      float pr0, pr1, nx0, nx1;
      if (p > 0)      { pr0 = acc0[r - 1]; pr1 = acc1[r - 1]; }
      else if (a > 0) { pr0 = q ? x0[a * 4 + 3] : x0[a * 4 - 1];
                        pr1 = q ? x1[a * 4 + 3] : x1[a * 4 - 1]; }
      else            { pr0 = q ? x0[3] : bp0;  pr1 = q ? x1[3] : bp1; }
      if (p < 3)      { nx0 = acc0[r + 1]; nx1 = acc1[r + 1]; }
      else if (a < 3) { nx0 = q ? x0[a * 4 + 4] : x0[a * 4];
                        nx1 = q ? x1[a * 4 + 4] : x1[a * 4]; }
      else            { nx0 = q ? bn0 : x0[12]; nx1 = q ? bn1 : x1[12]; }
      f32x2 v2;
      v2.x = (pr0 + acc0[r] + nx0) * T + bias0;
      v2.y = (pr1 + acc1[r] + nx1) * T + bias1;
      f32x2 ex; ex.x = __expf(-v2.x); ex.y = __expf(-v2.y);
      f32x2 den = ex + 1.0f;
      f32x2 y2;
      y2.x = v2.x * __builtin_amdgcn_rcpf(den.x);
      y2.y = v2.y * __builtin_amdgcn_rcpf(den.y);
      if constexpr (LAYER == 2) { ps0 += y2.x; ps1 += y2.y; }
      else {
        const int node = p + 8 * a + 4 * q;                 // local node 0..31
        scr3_w[node * 34 + c] = pk2bf(y2.x, y2.y);          // (hid c | hid c+32)
      }
    }

    if constexpr (LAYER == 2) {
      ps0 += __shfl_xor(ps0, 32);
      ps1 += __shfl_xor(ps1, 32);
      if (q == 0) { poolw[w * 256 + g * 64 + c]      = ps0;
                    poolw[w * 256 + g * 64 + 32 + c] = ps1; }
    } else {
      // rebuild A-frags for next layer (same-wave DS, in-order -> no barrier)
      const unsigned int* sb = scr3_w + c * 34;             // node = c row
      uint2 d0 = *(const uint2*)(sb + 8 * q + 0);
      uint2 d1 = *(const uint2*)(sb + 8 * q + 2);
      uint2 d2 = *(const uint2*)(sb + 8 * q + 4);
      uint2 d3 = *(const uint2*)(sb + 8 * q + 6);
      uint2 e0 = *(const uint2*)(sb + 16 + 8 * q + 0);
      uint2 e1 = *(const uint2*)(sb + 16 + 8 * q + 2);
      uint2 e2 = *(const uint2*)(sb + 16 + 8 * q + 4);
      uint2 e3 = *(const uint2*)(sb + 16 + 8 * q + 6);
      i32x4 f0 = { (int)lo_pack(d0.x, d0.y), (int)lo_pack(d1.x, d1.y),
                   (int)lo_pack(d2.x, d2.y), (int)lo_pack(d3.x, d3.y) };
      i32x4 f1 = { (int)lo_pack(e0.x, e0.y), (int)lo_pack(e1.x, e1.y),
                   (int)lo_pack(e2.x, e2.y), (int)lo_pack(e3.x, e3.y) };
      i32x4 f2v = { (int)hi_pack(d0.x, d0.y), (int)hi_pack(d1.x, d1.y),
                    (int)hi_pack(d2.x, d2.y), (int)hi_pack(d3.x, d3.y) };
      i32x4 f3 = { (int)hi_pack(e0.x, e0.y), (int)hi_pack(e1.x, e1.y),
                   (int)hi_pack(e2.x, e2.y), (int)hi_pack(e3.x, e3.y) };
      Anew[g * 4 + 0] = __builtin_bit_cast(bf16x8, f0);
      Anew[g * 4 + 1] = __builtin_bit_cast(bf16x8, f1);
      Anew[g * 4 + 2] = __builtin_bit_cast(bf16x8, f2v);
      Anew[g * 4 + 3] = __builtin_bit_cast(bf16x8, f3);
    }
  }
}

// ---------------- main fused kernel: 1 block = 1 graph, 8 waves x 32 nodes ----------
__global__ __launch_bounds__(512, 2) void poly_kernel(
    const float* __restrict__ x, const float* __restrict__ t,
    const float* __restrict__ tw, const float* __restrict__ tb,
    const unsigned short* __restrict__ packW,
    const float* __restrict__ B0, const float* __restrict__ B1,
    const float* __restrict__ B2, float* __restrict__ out) {
  __shared__ __align__(16) unsigned short lds_w[8192];     // 16 KiB W tile-0 stage
  __shared__ __align__(16) unsigned short bnd[4096];       //  8 KiB boundary (2 par x 8w x 2 x 64)
  __shared__ __align__(16) unsigned int   scr3[8 * 1088];  // 34 KiB per-wave packed transpose
  __shared__ __align__(16) unsigned short temb_sh[160];    // padded time embedding (bf16)

  const int tid = threadIdx.x;
  const int w = tid >> 6, lane = tid & 63;
  const int q = lane >> 5, c = lane & 31;
  const int b = blockIdx.x;

  // kick off layer-0 group-0 W staging immediately (overlaps the time MLP)
  stage(packW, lds_w, tid, w, 9 * 64);

  // ---- fused time MLP: temb = silu(sinemb(t[b]) @ tw + tb), padded [0x6, ., 0x10] ----
  {
    float* e_sh = (float*)bnd;        // 128 floats
    float* part = (float*)scr3;       // 512 float partials
    if (tid < 128) {
      const float tv = t[b];
      const int i = tid & 63;
      const float f = expf(-0.14619588396823767f * (float)i);  // log(1e4)/63
      const float ang = tv * f;
      e_sh[tid] = (tid < 64) ? sinf(ang) : cosf(ang);
    }
    __syncthreads();
    {
      const int j = tid & 127, p = tid >> 7;   // 4-way k-split over the block
      float a = 0.f;
#pragma unroll 8
      for (int kk = 0; kk < 32; ++kk) {
        const int k = p * 32 + kk;
        a += e_sh[k] * tw[k * 128 + j];
      }
      part[tid] = a;
    }
    __syncthreads();
    if (tid < 128) {
      const float a = tb[tid] + part[tid] + part[128 + tid] + part[256 + tid] + part[384 + tid];
      temb_sh[6 + tid] = f2bf(silu_f(a));
      if (tid < 6)  temb_sh[tid] = 0;
      if (tid < 10) temb_sh[134 + tid] = 0;
    }
    __syncthreads();
  }

  // build layer-0 A fragments: [coords(2), pe(4), temb(128), pad0(10)] = K 144
  bf16x8 A0[9], A1[16], A2[16];
  {
#pragma unroll
    for (int kt = 0; kt < 9; ++kt)
      A0[kt] = *(const bf16x8*)(temb_sh + kt * 16 + q * 8);
    if (q == 0) {  // k=0..5 live in q==0 lanes of k-tile 0
      const int n = w * 32 + c;                    // global node = A row m
      const float2 xy = ((const float2*)x)[b * 256 + n];
      const float th = 0.024543692605870074f * (float)n;   // 2*pi/256
      A0[0][0] = (short)f2bf(xy.x);
      A0[0][1] = (short)f2bf(xy.y);
      A0[0][2] = (short)f2bf(sinf(th));
      A0[0][3] = (short)f2bf(cosf(th));
      A0[0][4] = (short)f2bf(sinf(2.f * th));
      A0[0][5] = (short)f2bf(cosf(2.f * th));
    }
  }

  unsigned int* scr3_w = scr3 + w * 1088;
  float* poolw = (float*)scr3;   // layer-2 per-wave pool partials (transpose dead by then)
  gcn_layer< 9, 0>(tid, w, lane, q, c, packW,          packW + 36864,  1024,
                   B0, A0, A1, lds_w, bnd, scr3_w, poolw);
  gcn_layer<16, 1>(tid, w, lane, q, c, packW + 36864,  packW + 102400, 1024,
                   B1, A1, A2, lds_w, bnd, scr3_w, poolw);
  gcn_layer<16, 2>(tid, w, lane, q, c, packW + 102400, nullptr,        0,
                   B2, A2, A1, lds_w, bnd, scr3_w, poolw);

  __syncthreads();
  if (tid < 256) {
    float s = 0.f;
#pragma unroll
    for (int ww = 0; ww < 8; ++ww) s += poolw[ww * 256 + tid];
    out[b * 256 + tid] = s * (1.f / 256.f);
  }
}

// ---------------- launch ----------------
extern "C" void kernel_launch(void* const* d_in, const int* in_sizes, int n_in,
                              void* d_out, int out_size, void* d_ws, size_t ws_size,
                              hipStream_t stream) {
  const float* x  = (const float*)d_in[0];
  const float* t  = (const float*)d_in[1];
  const float* tw = (const float*)d_in[2];
  const float* tb = (const float*)d_in[3];
  const float* W0 = (const float*)d_in[4];
  const float* b0 = (const float*)d_in[5];
  const float* W1 = (const float*)d_in[6];
  const float* b1 = (const float*)d_in[7];
  const float* W2 = (const float*)d_in[8];
  const float* b2 = (const float*)d_in[9];

  unsigned short* packW = (unsigned short*)d_ws;   // 167936 shorts
  float* out = (float*)d_out;

  pack_kernel<<<656, 256, 0, stream>>>(W0, W1, W2, packW);
  poly_kernel<<<1024, 512, 0, stream>>>(x, t, tw, tb, packW, b0, b1, b2, out);
}

// Round 4
// 208.545 us; speedup vs baseline: 1.1879x; 1.1057x over previous
//
#include <hip/hip_runtime.h>
#include <cstdint>

typedef __attribute__((ext_vector_type(8)))  short bf16x8;   // 8 x bf16 (4 VGPR)
typedef __attribute__((ext_vector_type(16))) float f32x16;   // MFMA 32x32 acc
typedef __attribute__((ext_vector_type(2)))  float f32x2;
typedef __attribute__((ext_vector_type(4)))  int   i32x4;

__device__ __forceinline__ unsigned short f2bf(float x) {    // RNE fp32->bf16
  unsigned u = __float_as_uint(x);
  u += 0x7fffu + ((u >> 16) & 1u);
  return (unsigned short)(u >> 16);
}
__device__ __forceinline__ float bf2f(unsigned short h) {
  return __uint_as_float(((unsigned)h) << 16);
}
__device__ __forceinline__ float silu_f(float v) {
  return v * __builtin_amdgcn_rcpf(1.0f + __expf(-v));
}
// pack two fp32 -> bf16x2 dword (lo = first arg)
__device__ __forceinline__ unsigned pk2bf(float lo, float hi) {
#if defined(__has_builtin)
#if __has_builtin(__builtin_amdgcn_cvt_pk_bf16_f32)
  auto v = __builtin_amdgcn_cvt_pk_bf16_f32(lo, hi);
  unsigned u; __builtin_memcpy(&u, &v, 4); return u;
#else
  return ((unsigned)f2bf(hi) << 16) | (unsigned)f2bf(lo);
#endif
#else
  return ((unsigned)f2bf(hi) << 16) | (unsigned)f2bf(lo);
#endif
}
// v_perm lane-local byte select
__device__ __forceinline__ unsigned lo_pack(unsigned x, unsigned y) {
  return __builtin_amdgcn_perm(y, x, 0x05040100u);
}
__device__ __forceinline__ unsigned hi_pack(unsigned x, unsigned y) {
  return __builtin_amdgcn_perm(y, x, 0x07060302u);
}

// ---- pack W0/W1/W2 into MFMA B-frag order, bf16, K0 padded 134->144 (coalesced reads).
// layout: [layer][g(64 cols)][t(32-col tile)][kt][lane][8]
__global__ void pack_kernel(const float* __restrict__ W0, const float* __restrict__ W1,
                            const float* __restrict__ W2,
                            unsigned short* __restrict__ packW) {
  const int idx = blockIdx.x * 256 + threadIdx.x;          // 0..167935
  const float* W; int KT, kmax, base, lidx;
  if (idx < 36864)        { W = W0; KT = 9;  kmax = 134; base = 0;      lidx = idx; }
  else if (idx < 102400)  { W = W1; KT = 16; kmax = 256; base = 36864;  lidx = idx - 36864; }
  else                    { W = W2; KT = 16; kmax = 256; base = 102400; lidx = idx - 102400; }
  const int k   = lidx >> 8;                               // row of W (padded)
  const int col = lidx & 255;
  const float v = (k < kmax) ? W[k * 256 + col] : 0.0f;    // coalesced read
  const int kt = k >> 4, kr = k & 15, q = kr >> 3, j = kr & 7;
  const int g = col >> 6, t = (col >> 5) & 1, n = col & 31;
  const int dest = base + g * (KT * 1024) + t * (KT * 512) + kt * 512 + (q * 32 + n) * 8 + j;
  packW[dest] = f2bf(v);
}

// ---------------- one GCN layer, fully fused per graph ----------------
// Node mapping: A-row m holds node 32w + sig(m), sig(m)=(m&3)+4((m>>3)&3)+16((m>>2)&1).
// => C/D reg r of lane (q,c) holds node 32w + 16q + r  (16 consecutive nodes per half).
template <int KT, int LAYER>
__device__ __forceinline__ void gcn_layer(
    const int tid, const int w, const int lane, const int q, const int c, const int sig,
    const unsigned short* __restrict__ packL,
    const float* __restrict__ BIAS,
    const bf16x8* Aold, bf16x8* Anew,
    unsigned short* bnd, unsigned int* scr3_w, float* poolw) {
#pragma unroll
  for (int g = 0; g < 4; ++g) {
    const unsigned short* srcg = packL + g * (KT * 1024);

    // matmul: both B tiles streamed from global (L1/L2-resident weights), A in regs
    f32x16 acc0, acc1;
#pragma unroll
    for (int i = 0; i < 16; ++i) { acc0[i] = 0.f; acc1[i] = 0.f; }
    {
      const bf16x8* wb0 = (const bf16x8*)srcg;              // tile0 half
      const bf16x8* wb1 = (const bf16x8*)(srcg + KT * 512); // tile1 half
#pragma unroll
      for (int kt = 0; kt < KT; ++kt) {
        bf16x8 b0 = wb0[kt * 64 + lane];
        bf16x8 b1 = wb1[kt * 64 + lane];
        acc0 = __builtin_amdgcn_mfma_f32_32x32x16_bf16(Aold[kt], b0, acc0, 0, 0, 0);
        acc1 = __builtin_amdgcn_mfma_f32_32x32x16_bf16(Aold[kt], b1, acc1, 0, 0, 0);
      }
    }

    // publish wave-boundary s rows into bnd parity buffer:
    // entry w*2+0 = first node (32w), entry w*2+1 = last node (32w+31)
    unsigned short* bndp = bnd + (g & 1) * 2048;
    if (q == 0) { bndp[(w * 2 + 0) * 64 + c]      = f2bf(acc0[0]);
                  bndp[(w * 2 + 0) * 64 + 32 + c] = f2bf(acc1[0]); }
    else        { bndp[(w * 2 + 1) * 64 + c]      = f2bf(acc0[15]);
                  bndp[(w * 2 + 1) * 64 + 32 + c] = f2bf(acc1[15]); }
    __syncthreads();   // the single per-group barrier: bnd(g) visible to all waves

    // cross-half edge values (node 15 <-> node 16 of the wave's 32-node stripe)
    const float e0t0  = __shfl_xor(acc0[0], 32);   // other half's first-node s
    const float e0t1  = __shfl_xor(acc1[0], 32);
    const float e15t0 = __shfl_xor(acc0[15], 32);  // other half's last-node s
    const float e15t1 = __shfl_xor(acc1[15], 32);
    const float bp0 = bf2f(bndp[(((w + 7) & 7) * 2 + 1) * 64 + c]);        // node 32w-1
    const float bp1 = bf2f(bndp[(((w + 7) & 7) * 2 + 1) * 64 + 32 + c]);
    const float bn0 = bf2f(bndp[(((w + 1) & 7) * 2 + 0) * 64 + c]);        // node 32w+32
    const float bn1 = bf2f(bndp[(((w + 1) & 7) * 2 + 0) * 64 + 32 + c]);
    const float bias0 = BIAS[g * 64 + c], bias1 = BIAS[g * 64 + 32 + c];
    const float T = 0.33333333333f;
    float ps0 = 0.f, ps1 = 0.f;
#pragma unroll
    for (int r = 0; r < 16; ++r) {
      float pr0, pr1, nx0, nx1;
      if (r > 0)       { pr0 = acc0[r - 1]; pr1 = acc1[r - 1]; }
      else             { pr0 = q ? e15t0 : bp0; pr1 = q ? e15t1 : bp1; }
      if (r < 15)      { nx0 = acc0[r + 1]; nx1 = acc1[r + 1]; }
      else             { nx0 = q ? bn0 : e0t0; nx1 = q ? bn1 : e0t1; }
      f32x2 v2;
      v2.x = (pr0 + acc0[r] + nx0) * T + bias0;
      v2.y = (pr1 + acc1[r] + nx1) * T + bias1;
      f32x2 ex; ex.x = __expf(-v2.x); ex.y = __expf(-v2.y);
      f32x2 den = ex + 1.0f;
      f32x2 y2;
      y2.x = v2.x * __builtin_amdgcn_rcpf(den.x);
      y2.y = v2.y * __builtin_amdgcn_rcpf(den.y);
      if constexpr (LAYER == 2) { ps0 += y2.x; ps1 += y2.y; }
      else {
        scr3_w[(16 * q + r) * 34 + c] = pk2bf(y2.x, y2.y);  // row = true node-local idx
      }
    }

    if constexpr (LAYER == 2) {
      ps0 += __shfl_xor(ps0, 32);
      ps1 += __shfl_xor(ps1, 32);
      if (q == 0) { poolw[w * 256 + g * 64 + c]      = ps0;
                    poolw[w * 256 + g * 64 + 32 + c] = ps1; }
    } else {
      // rebuild A-frags for next layer (same-wave DS, in-order -> no barrier);
      // A-row m=c needs node-local sig(c)
      const unsigned int* sb = scr3_w + sig * 34;
      uint2 d0 = *(const uint2*)(sb + 8 * q + 0);
      uint2 d1 = *(const uint2*)(sb + 8 * q + 2);
      uint2 d2 = *(const uint2*)(sb + 8 * q + 4);
      uint2 d3 = *(const uint2*)(sb + 8 * q + 6);
      uint2 e0 = *(const uint2*)(sb + 16 + 8 * q + 0);
      uint2 e1 = *(const uint2*)(sb + 16 + 8 * q + 2);
      uint2 e2 = *(const uint2*)(sb + 16 + 8 * q + 4);
      uint2 e3 = *(const uint2*)(sb + 16 + 8 * q + 6);
      i32x4 f0 = { (int)lo_pack(d0.x, d0.y), (int)lo_pack(d1.x, d1.y),
                   (int)lo_pack(d2.x, d2.y), (int)lo_pack(d3.x, d3.y) };
      i32x4 f1 = { (int)lo_pack(e0.x, e0.y), (int)lo_pack(e1.x, e1.y),
                   (int)lo_pack(e2.x, e2.y), (int)lo_pack(e3.x, e3.y) };
      i32x4 f2v = { (int)hi_pack(d0.x, d0.y), (int)hi_pack(d1.x, d1.y),
                    (int)hi_pack(d2.x, d2.y), (int)hi_pack(d3.x, d3.y) };
      i32x4 f3 = { (int)hi_pack(e0.x, e0.y), (int)hi_pack(e1.x, e1.y),
                   (int)hi_pack(e2.x, e2.y), (int)hi_pack(e3.x, e3.y) };
      Anew[g * 4 + 0] = __builtin_bit_cast(bf16x8, f0);
      Anew[g * 4 + 1] = __builtin_bit_cast(bf16x8, f1);
      Anew[g * 4 + 2] = __builtin_bit_cast(bf16x8, f2v);
      Anew[g * 4 + 3] = __builtin_bit_cast(bf16x8, f3);
    }
  }
}

// ---------------- main fused kernel: 1 block = 1 graph, 8 waves x 32 nodes ----------
__global__ __launch_bounds__(512, 2) void poly_kernel(
    const float* __restrict__ x, const float* __restrict__ t,
    const float* __restrict__ tw, const float* __restrict__ tb,
    const unsigned short* __restrict__ packW,
    const float* __restrict__ B0, const float* __restrict__ B1,
    const float* __restrict__ B2, float* __restrict__ out) {
  __shared__ __align__(16) unsigned short bnd[4096];       // 8 KiB boundary (2 par x 8w x 2 x 64)
  __shared__ __align__(16) unsigned int   scr3[8 * 1088];  // 34 KiB per-wave packed transpose
  __shared__ __align__(16) unsigned short temb_sh[160];    // padded time embedding (bf16)

  const int tid = threadIdx.x;
  const int w = tid >> 6, lane = tid & 63;
  const int q = lane >> 5, c = lane & 31;
  const int b = blockIdx.x;
  // sig(c): node-local index held by A-row m=c
  const int sig = (c & 3) + 4 * ((c >> 3) & 3) + 16 * ((c >> 2) & 1);

  // ---- fused time MLP: temb = silu(sinemb(t[b]) @ tw + tb), padded [0x6, ., 0x10] ----
  {
    float* e_sh = (float*)bnd;        // 128 floats
    float* part = (float*)scr3;       // 512 float partials
    if (tid < 128) {
      const float tv = t[b];
      const int i = tid & 63;
      const float f = expf(-0.14619588396823767f * (float)i);  // log(1e4)/63
      const float ang = tv * f;
      e_sh[tid] = (tid < 64) ? sinf(ang) : cosf(ang);
    }
    __syncthreads();
    {
      const int j = tid & 127, p = tid >> 7;   // 4-way k-split over the block
      float a = 0.f;
#pragma unroll 8
      for (int kk = 0; kk < 32; ++kk) {
        const int k = p * 32 + kk;
        a += e_sh[k] * tw[k * 128 + j];
      }
      part[tid] = a;
    }
    __syncthreads();
    if (tid < 128) {
      const float a = tb[tid] + part[tid] + part[128 + tid] + part[256 + tid] + part[384 + tid];
      temb_sh[6 + tid] = f2bf(silu_f(a));
      if (tid < 6)  temb_sh[tid] = 0;
      if (tid < 10) temb_sh[134 + tid] = 0;
    }
    __syncthreads();
  }

  // build layer-0 A fragments: [coords(2), pe(4), temb(128), pad0(10)] = K 144
  bf16x8 A0[9], A1[16], A2[16];
  {
#pragma unroll
    for (int kt = 0; kt < 9; ++kt)
      A0[kt] = *(const bf16x8*)(temb_sh + kt * 16 + q * 8);
    if (q == 0) {  // k=0..5 live in q==0 lanes of k-tile 0; A-row m=c holds node 32w+sig
      const int n = w * 32 + sig;
      const float2 xy = ((const float2*)x)[b * 256 + n];
      const float th = 0.024543692605870074f * (float)n;   // 2*pi/256
      A0[0][0] = (short)f2bf(xy.x);
      A0[0][1] = (short)f2bf(xy.y);
      A0[0][2] = (short)f2bf(sinf(th));
      A0[0][3] = (short)f2bf(cosf(th));
      A0[0][4] = (short)f2bf(sinf(2.f * th));
      A0[0][5] = (short)f2bf(cosf(2.f * th));
    }
  }

  unsigned int* scr3_w = scr3 + w * 1088;
  float* poolw = (float*)scr3;   // layer-2 per-wave pool partials (transpose dead by then)
  gcn_layer< 9, 0>(tid, w, lane, q, c, sig, packW,          B0, A0, A1, bnd, scr3_w, poolw);
  gcn_layer<16, 1>(tid, w, lane, q, c, sig, packW + 36864,  B1, A1, A2, bnd, scr3_w, poolw);
  gcn_layer<16, 2>(tid, w, lane, q, c, sig, packW + 102400, B2, A2, A1, bnd, scr3_w, poolw);

  __syncthreads();
  if (tid < 256) {
    float s = 0.f;
#pragma unroll
    for (int ww = 0; ww < 8; ++ww) s += poolw[ww * 256 + tid];
    out[b * 256 + tid] = s * (1.f / 256.f);
  }
}

// ---------------- launch ----------------
extern "C" void kernel_launch(void* const* d_in, const int* in_sizes, int n_in,
                              void* d_out, int out_size, void* d_ws, size_t ws_size,
                              hipStream_t stream) {
  const float* x  = (const float*)d_in[0];
  const float* t  = (const float*)d_in[1];
  const float* tw = (const float*)d_in[2];
  const float* tb = (const float*)d_in[3];
  const float* W0 = (const float*)d_in[4];
  const float* b0 = (const float*)d_in[5];
  const float* W1 = (const float*)d_in[6];
  const float* b1 = (const float*)d_in[7];
  const float* W2 = (const float*)d_in[8];
  const float* b2 = (const float*)d_in[9];

  unsigned short* packW = (unsigned short*)d_ws;   // 167936 shorts
  float* out = (float*)d_out;

  pack_kernel<<<656, 256, 0, stream>>>(W0, W1, W2, packW);
  poly_kernel<<<1024, 512, 0, stream>>>(x, t, tw, tb, packW, b0, b1, b2, out);
}